// Round 10
// baseline (938.468 us; speedup 1.0000x reference)
//
#include <hip/hip_runtime.h>
#include <hip/hip_fp16.h>

// ---------------------------------------------------------------------------
// GATv2 3-layer GNN encoder. N=50000 nodes, E=800000 edges, dims 128.
// CSR build (multi-block scan) + degree-sort + fp16 edge-stream permute
// (split convert/permute); per layer: [prep_w, MFMA dual GEMM, fused
// edge-score (fdot2, ea via per-wave LDS staging) + softmax + agg + LN].
// ---------------------------------------------------------------------------

typedef __attribute__((ext_vector_type(8))) short bf16x8;
typedef __attribute__((ext_vector_type(4))) float f32x4;
typedef __fp16 h2 __attribute__((ext_vector_type(2)));

__device__ inline ushort f2bf(float f) {
  unsigned u = __float_as_uint(f);
  u += 0x7FFF + ((u >> 16) & 1);
  return (ushort)(u >> 16);
}

__device__ inline ushort f2h(float f) {
  __half h = __float2half(f);
  return *(ushort*)&h;
}

__device__ inline uint pk2(float a, float b) {
#if __has_builtin(__builtin_amdgcn_cvt_pkrtz)
  h2 r = __builtin_amdgcn_cvt_pkrtz(a, b);
  return *(uint*)&r;
#else
  return (uint)f2h(a) | ((uint)f2h(b) << 16);
#endif
}

__device__ inline float fdot2(uint a, uint b, float c) {
#if __has_builtin(__builtin_amdgcn_fdot2)
  return __builtin_amdgcn_fdot2(*(h2*)&a, *(h2*)&b, c, false);
#else
  float2 fa = __half22float2(*(__half2*)&a);
  float2 fb = __half22float2(*(__half2*)&b);
  return c + fa.x * fb.x + fa.y * fb.y;
#endif
}

__device__ inline uint swz_add(uint p, int o) {
  int q = __shfl_xor(*(int*)&p, o);
  __half2 r = __hadd2(*(__half2*)&p, *(__half2*)&q);
  return *(uint*)&r;
}

// ---------------- CSR build ----------------

__global__ __launch_bounds__(256) void hist_kernel(const int* __restrict__ dst,
                                                   int* __restrict__ deg, int nE) {
  int i = blockIdx.x * 256 + threadIdx.x;
  if (i < nE) atomicAdd(&deg[dst[i]], 1);
}

// phase 1: per-block inclusive scan of 1024 elems -> rowptr[i+1], block total.
__global__ __launch_bounds__(1024) void scan_blocks(const int* __restrict__ deg,
                                                    int* __restrict__ rowptr,
                                                    int* __restrict__ bsum, int n) {
  __shared__ int wsum[16];
  __shared__ int wbase[16];
  int tid = threadIdx.x, wid = tid >> 6, lane = tid & 63;
  int i = blockIdx.x * 1024 + tid;
  int v = (i < n) ? deg[i] : 0;
#pragma unroll
  for (int o = 1; o < 64; o <<= 1) {
    int t = __shfl_up(v, o);
    if (lane >= o) v += t;
  }
  if (lane == 63) wsum[wid] = v;
  __syncthreads();
  if (tid < 16) {
    int s = wsum[tid];
#pragma unroll
    for (int o = 1; o < 16; o <<= 1) {
      int t = __shfl_up(s, o);
      if (tid >= o) s += t;
    }
    wbase[tid] = s;
  }
  __syncthreads();
  int base = (wid > 0) ? wbase[wid - 1] : 0;
  if (i < n) rowptr[i + 1] = base + v;
  if (tid == 1023) bsum[blockIdx.x] = wbase[15];
}

// phase 2: exclusive scan of block totals (single wave, looped).
__global__ __launch_bounds__(64) void scan_carry(int* __restrict__ bsum, int nb) {
  int lane = threadIdx.x;
  int carry = 0;
  for (int base = 0; base < nb; base += 64) {
    int i = base + lane;
    int v = (i < nb) ? bsum[i] : 0;
    int inc = v;
#pragma unroll
    for (int o = 1; o < 64; o <<= 1) {
      int t = __shfl_up(inc, o);
      if (lane >= o) inc += t;
    }
    if (i < nb) bsum[i] = carry + inc - v;  // exclusive
    carry += __shfl(inc, 63);
  }
}

// phase 3: add block bases.
__global__ __launch_bounds__(1024) void scan_apply(int* __restrict__ rowptr,
                                                   const int* __restrict__ bsum, int n) {
  int i = blockIdx.x * 1024 + threadIdx.x;
  if (i < n) rowptr[i + 1] += bsum[blockIdx.x];
  if (i == 0) rowptr[0] = 0;
}

__global__ __launch_bounds__(256) void scatter_kernel(const int* __restrict__ dst,
                                                      const int* __restrict__ rowptr,
                                                      int* __restrict__ cnt,
                                                      int* __restrict__ eperm, int nE) {
  int i = blockIdx.x * 256 + threadIdx.x;
  if (i < nE) {
    int d = dst[i];
    int p = atomicAdd(&cnt[d], 1);
    eperm[rowptr[d] + p] = i;
  }
}

__global__ __launch_bounds__(256) void deg_hist(const int* __restrict__ rowptr,
                                                int* __restrict__ dh, int nN) {
  int i = blockIdx.x * 256 + threadIdx.x;
  if (i < nN) {
    int dg = min(rowptr[i + 1] - rowptr[i], 255);
    atomicAdd(&dh[dg], 1);
  }
}

__global__ __launch_bounds__(256) void deg_scan(const int* __restrict__ dh,
                                                int* __restrict__ dbase) {
  __shared__ int s[256];
  int t = threadIdx.x;
  s[t] = dh[t];
  __syncthreads();
  for (int ofs = 1; ofs < 256; ofs <<= 1) {
    int v = (t >= ofs) ? s[t - ofs] : 0;
    __syncthreads();
    s[t] += v;
    __syncthreads();
  }
  dbase[t] = s[255] - s[t];
}

__global__ __launch_bounds__(256) void deg_scatter(const int* __restrict__ rowptr,
                                                   const int* __restrict__ dbase,
                                                   int* __restrict__ dcnt,
                                                   int* __restrict__ nodeorder, int nN) {
  int i = blockIdx.x * 256 + threadIdx.x;
  if (i < nN) {
    int dg = min(rowptr[i + 1] - rowptr[i], 255);
    int p = atomicAdd(&dcnt[dg], 1);
    nodeorder[dbase[dg] + p] = i;
  }
}

// ---------------- edge stream prep ----------------

// sequential fp32 -> fp16 (full-BW stream)
__global__ __launch_bounds__(256) void convert_ea(const float* __restrict__ ea,
                                                  ushort* __restrict__ tmp, int n8) {
  int i = blockIdx.x * 256 + threadIdx.x;
  if (i < n8) {
    float4 a = ((const float4*)ea)[i * 2];
    float4 b = ((const float4*)ea)[i * 2 + 1];
    union { ushort r[8]; uint4 v; } u;
    u.r[0] = f2h(a.x); u.r[1] = f2h(a.y); u.r[2] = f2h(a.z); u.r[3] = f2h(a.w);
    u.r[4] = f2h(b.x); u.r[5] = f2h(b.y); u.r[6] = f2h(b.z); u.r[7] = f2h(b.w);
    ((uint4*)tmp)[i] = u.v;
  }
}

// CSR-order permute of the fp16 stream (4 threads x 16B per edge row)
__global__ __launch_bounds__(256) void permute_ea(const ushort* __restrict__ tmp,
                                                  const int* __restrict__ eperm,
                                                  const int* __restrict__ src,
                                                  ushort* __restrict__ ea16,
                                                  int* __restrict__ src_perm, int nE) {
  int t = blockIdx.x * 256 + threadIdx.x;
  int j = t >> 2, part = t & 3;
  if (j < nE) {
    int e = eperm[j];
    ((uint4*)&ea16[(size_t)j * 32])[part] =
        ((const uint4*)&tmp[(size_t)e * 32])[part];
    if (part == 0) src_perm[j] = src[e];
  }
}

// fallback: fused convert+permute straight from fp32 (used if ws is tight)
template <bool PERM>
__global__ __launch_bounds__(256) void prep_edges_h(const float* __restrict__ ea,
                                                    const int* __restrict__ eperm,
                                                    const int* __restrict__ src,
                                                    ushort* __restrict__ ea16,
                                                    int* __restrict__ src_perm, int nE) {
  int t = blockIdx.x * 256 + threadIdx.x;
  int j = t >> 3, ch = (t & 7) << 2;
  if (j < nE) {
    int e = PERM ? eperm[j] : j;
    float4 v = *(const float4*)&ea[(size_t)e * 32 + ch];
    ushort4 h;
    h.x = f2h(v.x); h.y = f2h(v.y); h.z = f2h(v.z); h.w = f2h(v.w);
    *(ushort4*)&ea16[(size_t)j * 32 + ch] = h;
    if (PERM && ch == 0) src_perm[j] = src[e];
  }
}

// ---------------- bf16 prep ----------------

__global__ __launch_bounds__(256) void convert_x(const float* __restrict__ x,
                                                 ushort* __restrict__ xb, int n8) {
  int i = blockIdx.x * 256 + threadIdx.x;
  if (i < n8) {
    float4 a = ((const float4*)x)[i * 2];
    float4 b = ((const float4*)x)[i * 2 + 1];
    union { ushort r[8]; uint4 v; } u;
    u.r[0] = f2bf(a.x); u.r[1] = f2bf(a.y); u.r[2] = f2bf(a.z); u.r[3] = f2bf(a.w);
    u.r[4] = f2bf(b.x); u.r[5] = f2bf(b.y); u.r[6] = f2bf(b.z); u.r[7] = f2bf(b.w);
    ((uint4*)xb)[i] = u.v;
  }
}

__global__ __launch_bounds__(256) void prep_w(const float* __restrict__ Wl,
                                              const float* __restrict__ Wr,
                                              ushort* __restrict__ wt1,
                                              ushort* __restrict__ wt2) {
  int idx = blockIdx.x * 256 + threadIdx.x;
  int mat = idx >> 14, rem = idx & 16383;
  int n = rem >> 7, k = rem & 127;
  const float* W = mat ? Wr : Wl;
  ushort* wt = mat ? wt2 : wt1;
  wt[n * 128 + k] = f2bf(W[(size_t)k * 128 + n]);
}

// ---------------- MFMA dual GEMM ----------------
#define XPAD 136

__device__ inline bf16x8 load_frag(const ushort* p) {
  union { bf16x8 v; unsigned long long q[2]; } u;
  u.q[0] = *(const unsigned long long*)p;
  u.q[1] = *(const unsigned long long*)(p + 16);
  return u.v;
}

__global__ __launch_bounds__(512) void gemm_mfma_dual(
    const ushort* __restrict__ xb, const ushort* __restrict__ wt1,
    const ushort* __restrict__ wt2, const float* __restrict__ b1,
    const float* __restrict__ b2, ushort* __restrict__ xlh,
    float* __restrict__ y2, int nrows) {
  __shared__ ushort Xs[128 * XPAD];
  __shared__ ushort Ws[128 * XPAD];
  const int tid = threadIdx.x;
  const int r0 = blockIdx.x * 128;

#pragma unroll
  for (int i = 0; i < 4; ++i) {
    int c = tid + i * 512;
    int row = c >> 4, kc = (c & 15) << 3;
    int gr = min(r0 + row, nrows - 1);
    *(uint4*)&Xs[row * XPAD + kc] = *(const uint4*)&xb[(size_t)gr * 128 + kc];
    *(uint4*)&Ws[row * XPAD + kc] = *(const uint4*)&wt1[row * 128 + kc];
  }
  __syncthreads();

  const int wid = tid >> 6, lane = tid & 63;
  const int lr = lane & 15, lg = lane >> 4;
  const int RB = (wid & 3) * 32, CB = (wid >> 2) * 64;

  f32x4 acc1[2][4] = {{{0.f}}};
  f32x4 acc2[2][4] = {{{0.f}}};

#pragma unroll
  for (int ks = 0; ks < 4; ++ks) {
    const int kb = ks * 32 + lg * 4;
    bf16x8 a0 = load_frag(&Xs[(RB + lr) * XPAD + kb]);
    bf16x8 a1 = load_frag(&Xs[(RB + 16 + lr) * XPAD + kb]);
#pragma unroll
    for (int nt = 0; nt < 4; ++nt) {
      const int n = CB + nt * 16 + lr;
      bf16x8 bw = load_frag(&Ws[n * XPAD + kb]);
      acc1[0][nt] = __builtin_amdgcn_mfma_f32_16x16x32_bf16(a0, bw, acc1[0][nt], 0, 0, 0);
      acc1[1][nt] = __builtin_amdgcn_mfma_f32_16x16x32_bf16(a1, bw, acc1[1][nt], 0, 0, 0);
    }
  }
  __syncthreads();
#pragma unroll
  for (int i = 0; i < 4; ++i) {
    int c = tid + i * 512;
    int row = c >> 4, kc = (c & 15) << 3;
    *(uint4*)&Ws[row * XPAD + kc] = *(const uint4*)&wt2[row * 128 + kc];
  }
  __syncthreads();
#pragma unroll
  for (int ks = 0; ks < 4; ++ks) {
    const int kb = ks * 32 + lg * 4;
    bf16x8 a0 = load_frag(&Xs[(RB + lr) * XPAD + kb]);
    bf16x8 a1 = load_frag(&Xs[(RB + 16 + lr) * XPAD + kb]);
#pragma unroll
    for (int nt = 0; nt < 4; ++nt) {
      const int n = CB + nt * 16 + lr;
      bf16x8 bw = load_frag(&Ws[n * XPAD + kb]);
      acc2[0][nt] = __builtin_amdgcn_mfma_f32_16x16x32_bf16(a0, bw, acc2[0][nt], 0, 0, 0);
      acc2[1][nt] = __builtin_amdgcn_mfma_f32_16x16x32_bf16(a1, bw, acc2[1][nt], 0, 0, 0);
    }
  }

#pragma unroll
  for (int nt = 0; nt < 4; ++nt) {
    const int col = CB + nt * 16 + lr;
    const float bb1 = b1[col], bb2 = b2[col];
    const int hoff = ((col & 63) << 1) | (col >> 6);
#pragma unroll
    for (int mt = 0; mt < 2; ++mt) {
#pragma unroll
      for (int r = 0; r < 4; ++r) {
        int gr = r0 + RB + mt * 16 + lg * 4 + r;
        if (gr < nrows) {
          xlh[(size_t)gr * 128 + hoff] = f2h(acc1[mt][nt][r] + bb1);
          y2[(size_t)gr * 128 + col] = acc2[mt][nt][r] + bb2;
        }
      }
    }
  }
}

// ---------------- fused GATv2 layer ----------------
// ONE 64-lane wave per node. ea16 rows staged per-wave into private LDS
// (coalesced global->LDS, then broadcast ds_read_b128 per edge) -- off the
// VALU/SGPR path. 8 edges in flight; packed-f16 reduce; no barriers.
template <int H, bool OB, bool PERM>
__global__ __launch_bounds__(256) void fused_gat(const ushort* __restrict__ xlh,
                                                 const float* __restrict__ xr,
                                                 const ushort* __restrict__ ea16,
                                                 const float* __restrict__ We,
                                                 const float* __restrict__ att,
                                                 const int* __restrict__ rowptr,
                                                 const int* __restrict__ eperm,
                                                 const int* __restrict__ src,
                                                 const int* __restrict__ nodeorder,
                                                 const float* __restrict__ bias,
                                                 const float* __restrict__ gam,
                                                 const float* __restrict__ bet,
                                                 float* __restrict__ out,
                                                 ushort* __restrict__ outb, int nN,
                                                 int nE) {
  __shared__ uint4 eas[4][256];  // per-wave slice: 64 edges x 64B
  const int wid = threadIdx.x >> 6;
  const int lane = threadIdx.x & 63;
  const int bn = blockIdx.x * 4 + wid;
  if (bn >= nN) return;
  const int n = __builtin_amdgcn_readfirstlane(nodeorder[bn]);
  const int rb = __builtin_amdgcn_readfirstlane(rowptr[n]);
  const int re = __builtin_amdgcn_readfirstlane(rowptr[n + 1]);
  const int cL = lane, cH = lane + 64;
  const uint* __restrict__ xlw = (const uint*)xlh;

  uint WcLp[16], WcHp[16];
#pragma unroll
  for (int k = 0; k < 16; ++k) {
    WcLp[k] = pk2(We[(2 * k) * 128 + cL], We[(2 * k + 1) * 128 + cL]);
    WcHp[k] = pk2(We[(2 * k) * 128 + cH], We[(2 * k + 1) * 128 + cH]);
  }
#pragma unroll
  for (int k = 0; k < 16; ++k) {
    asm volatile("" : "+v"(WcLp[k]), "+v"(WcHp[k]));
  }
  const float attL = att[cL] * 1.44269504088896f;
  const float attH = att[cH] * 1.44269504088896f;
  const float xrL = xr[(size_t)n * 128 + cL];
  const float xrH = xr[(size_t)n * 128 + cH];
  const size_t maxoff = (size_t)nE * 64 - 16;  // ea16 byte clamp

  float dL = 0.f, dH = 0.f, accL = 0.f, accH = 0.f;

  for (int b0 = rb; b0 < re; b0 += 64) {
    const int cnt = min(64, re - b0);
    const int jj = b0 + lane;
    int sv, ev = 0;
    if (PERM) {
      sv = (jj < re) ? src[jj] : 0;
    } else {
      ev = (jj < re) ? eperm[jj] : 0;
      sv = (jj < re) ? src[ev] : 0;
    }

    // stage this batch's ea16 rows into the wave's LDS slice (no barrier:
    // per-wave private; same-wave ds ordering via waitcnt)
#pragma unroll
    for (int it = 0; it < 4; ++it) {
      int c = it * 64 + lane;  // 16B chunk id, 4 chunks per edge
      size_t goff;
      if (PERM) {
        goff = (size_t)b0 * 64 + (size_t)c * 16;
        if (goff > maxoff) goff = maxoff;  // clamp at buffer end (masked later)
      } else {
        int ee = __shfl(ev, c >> 2);
        goff = (size_t)ee * 64 + (size_t)(c & 3) * 16;
      }
      eas[wid][c] = *(const uint4*)((const char*)ea16 + goff);
    }

    for (int i = 0; i < cnt; i += 8) {
      uint uu[8];
      float fx[8], fy[8], pl[8], ph[8];
#pragma unroll
      for (int j = 0; j < 8; ++j) {  // issue all gathers first
        int ij = min(i + j, cnt - 1);
        int sj = __builtin_amdgcn_readlane(sv, ij);
        uu[j] = xlw[(size_t)sj * 64 + lane];
      }
#pragma unroll
      for (int j = 0; j < 8; ++j) {
        const int ij = i + j;  // unclamped: garbage rows masked below
        uint4 q0 = eas[wid][(ij << 2) + 0];  // broadcast ds_read_b128
        uint4 q1 = eas[wid][(ij << 2) + 1];
        uint4 q2 = eas[wid][(ij << 2) + 2];
        uint4 q3 = eas[wid][(ij << 2) + 3];
        float2 f = __half22float2(*(__half2*)&uu[j]);
        float mL = f.x + xrL, mH = f.y + xrH;
        mL = fdot2(q0.x, WcLp[0], mL);  mH = fdot2(q0.x, WcHp[0], mH);
        mL = fdot2(q0.y, WcLp[1], mL);  mH = fdot2(q0.y, WcHp[1], mH);
        mL = fdot2(q0.z, WcLp[2], mL);  mH = fdot2(q0.z, WcHp[2], mH);
        mL = fdot2(q0.w, WcLp[3], mL);  mH = fdot2(q0.w, WcHp[3], mH);
        mL = fdot2(q1.x, WcLp[4], mL);  mH = fdot2(q1.x, WcHp[4], mH);
        mL = fdot2(q1.y, WcLp[5], mL);  mH = fdot2(q1.y, WcHp[5], mH);
        mL = fdot2(q1.z, WcLp[6], mL);  mH = fdot2(q1.z, WcHp[6], mH);
        mL = fdot2(q1.w, WcLp[7], mL);  mH = fdot2(q1.w, WcHp[7], mH);
        mL = fdot2(q2.x, WcLp[8], mL);  mH = fdot2(q2.x, WcHp[8], mH);
        mL = fdot2(q2.y, WcLp[9], mL);  mH = fdot2(q2.y, WcHp[9], mH);
        mL = fdot2(q2.z, WcLp[10], mL); mH = fdot2(q2.z, WcHp[10], mH);
        mL = fdot2(q2.w, WcLp[11], mL); mH = fdot2(q2.w, WcHp[11], mH);
        mL = fdot2(q3.x, WcLp[12], mL); mH = fdot2(q3.x, WcHp[12], mH);
        mL = fdot2(q3.y, WcLp[13], mL); mH = fdot2(q3.y, WcHp[13], mH);
        mL = fdot2(q3.z, WcLp[14], mL); mH = fdot2(q3.z, WcHp[14], mH);
        mL = fdot2(q3.w, WcLp[15], mL); mH = fdot2(q3.w, WcHp[15], mH);
        fx[j] = f.x;
        fy[j] = f.y;
        pl[j] = fmaxf(mL, 0.2f * mL) * attL;
        ph[j] = fmaxf(mH, 0.2f * mH) * attH;
      }
#pragma unroll
      for (int pr = 0; pr < 4; ++pr) {
        const int a = 2 * pr, b = 2 * pr + 1;
        uint packL, packH;
        if (H == 4) {
          packL = pk2(pl[a], pl[b]);
          packH = pk2(ph[a], ph[b]);
#pragma unroll
          for (int o = 16; o >= 1; o >>= 1) {
            packL = swz_add(packL, o);
            packH = swz_add(packH, o);
          }
        } else {
          packL = pk2(pl[a] + ph[a], pl[b] + ph[b]);
#pragma unroll
          for (int o = 32; o >= 1; o >>= 1) {
            packL = swz_add(packL, o);
          }
          packH = packL;
        }
        float2 sL = __half22float2(*(__half2*)&packL);
        float2 sH = __half22float2(*(__half2*)&packH);
        float wLa = exp2f(fminf(sL.x, 115.f));
        float wLb = exp2f(fminf(sL.y, 115.f));
        float wHa = exp2f(fminf(sH.x, 115.f));
        float wHb = exp2f(fminf(sH.y, 115.f));
        if (i + a >= cnt) { wLa = 0.f; wHa = 0.f; }
        if (i + b >= cnt) { wLb = 0.f; wHb = 0.f; }
        dL += wLa + wLb;
        dH += wHa + wHb;
        accL += wLa * fx[a] + wLb * fx[b];
        accH += wHa * fy[a] + wHb * fy[b];
      }
    }
  }

  const float rdL = (dL > 0.f) ? 1.f / dL : 0.f;
  const float rdH = (dH > 0.f) ? 1.f / dH : 0.f;
  float y0 = accL * rdL + bias[cL];
  float y1 = accH * rdH + bias[cH];

  float sm = y0 + y1, sq = y0 * y0 + y1 * y1;
#pragma unroll
  for (int o = 32; o >= 1; o >>= 1) {
    sm += __shfl_xor(sm, o);
    sq += __shfl_xor(sq, o);
  }
  const float mu = sm * (1.f / 128.f);
  const float var = sq * (1.f / 128.f) - mu * mu;
  const float rstd = rsqrtf(var + 1e-5f);
  const float o0 = fmaxf((y0 - mu) * rstd * gam[cL] + bet[cL], 0.f);
  const float o1 = fmaxf((y1 - mu) * rstd * gam[cH] + bet[cH], 0.f);
  if (OB) {
    outb[(size_t)n * 128 + cL] = f2bf(o0);
    outb[(size_t)n * 128 + cH] = f2bf(o1);
  } else {
    out[(size_t)n * 128 + cL] = o0;
    out[(size_t)n * 128 + cH] = o1;
  }
}

extern "C" void kernel_launch(void* const* d_in, const int* in_sizes, int n_in,
                              void* d_out, int out_size, void* d_ws, size_t ws_size,
                              hipStream_t stream) {
  const float* x = (const float*)d_in[0];
  const float* ea = (const float*)d_in[1];
  const int* src = (const int*)d_in[2];
  const int* dst = (const int*)d_in[3];
  const int N = in_sizes[0] / 128;
  const int E = in_sizes[2];

  char* w = (char*)d_ws;
  auto alloc = [&](size_t bytes) {
    char* p = w;
    w += (bytes + 255) & ~(size_t)255;
    return p;
  };
  ushort* xlh = (ushort*)alloc((size_t)N * 128 * 2);
  float* xr = (float*)alloc((size_t)N * 128 * 4);
  ushort* xb = (ushort*)alloc((size_t)N * 128 * 2);
  ushort* wt1 = (ushort*)alloc(128 * 128 * 2);
  ushort* wt2 = (ushort*)alloc(128 * 128 * 2);
  int* eperm = (int*)alloc((size_t)E * 4);
  int* rowptr = (int*)alloc((size_t)(N + 1) * 4);
  int* deg = (int*)alloc((size_t)N * 4);
  int* cnt = (int*)alloc((size_t)N * 4);
  int* nodeorder = (int*)alloc((size_t)N * 4);
  int* dh = (int*)alloc(256 * 4);
  int* dbase = (int*)alloc(256 * 4);
  int* dcnt = (int*)alloc(256 * 4);
  int* bsum = (int*)alloc(1024 * 4);
  ushort* ea16 = (ushort*)alloc((size_t)E * 32 * 2);
  size_t used = (size_t)(w - (char*)d_ws);
  const bool PERM_OK = (used + (size_t)E * 4 + 256 <= ws_size);
  int* src_perm = nullptr;
  if (PERM_OK) src_perm = (int*)alloc((size_t)E * 4);
  used = (size_t)(w - (char*)d_ws);
  const bool SPLIT_OK = PERM_OK && (used + (size_t)E * 32 * 2 + 256 <= ws_size);
  ushort* tmp16 = nullptr;
  if (SPLIT_OK) tmp16 = (ushort*)alloc((size_t)E * 32 * 2);

  hipMemsetAsync(deg, 0, (size_t)N * 4, stream);
  hipMemsetAsync(cnt, 0, (size_t)N * 4, stream);
  hipMemsetAsync(dh, 0, 256 * 4, stream);
  hipMemsetAsync(dcnt, 0, 256 * 4, stream);
  hist_kernel<<<(E + 255) / 256, 256, 0, stream>>>(dst, deg, E);
  int nb = (N + 1023) / 1024;
  scan_blocks<<<nb, 1024, 0, stream>>>(deg, rowptr, bsum, N);
  scan_carry<<<1, 64, 0, stream>>>(bsum, nb);
  scan_apply<<<nb, 1024, 0, stream>>>(rowptr, bsum, N);
  scatter_kernel<<<(E + 255) / 256, 256, 0, stream>>>(dst, rowptr, cnt, eperm, E);
  deg_hist<<<(N + 255) / 256, 256, 0, stream>>>(rowptr, dh, N);
  deg_scan<<<1, 256, 0, stream>>>(dh, dbase);
  deg_scatter<<<(N + 255) / 256, 256, 0, stream>>>(rowptr, dbase, dcnt, nodeorder, N);

  if (SPLIT_OK) {
    convert_ea<<<(E * 4 + 255) / 256, 256, 0, stream>>>(ea, tmp16, E * 4);
    permute_ea<<<((size_t)E * 4 + 255) / 256, 256, 0, stream>>>(tmp16, eperm, src,
                                                                ea16, src_perm, E);
  } else if (PERM_OK) {
    prep_edges_h<true><<<((size_t)E * 8 + 255) / 256, 256, 0, stream>>>(
        ea, eperm, src, ea16, src_perm, E);
  } else {
    prep_edges_h<false><<<((size_t)E * 8 + 255) / 256, 256, 0, stream>>>(
        ea, eperm, src, ea16, nullptr, E);
  }

  int n8 = N * 128 / 8;
  convert_x<<<(n8 + 255) / 256, 256, 0, stream>>>(x, xb, n8);

  for (int l = 0; l < 3; ++l) {
    int bi = 4 + 9 * l;
    const float* Wl = (const float*)d_in[bi + 0];
    const float* bl = (const float*)d_in[bi + 1];
    const float* Wr = (const float*)d_in[bi + 2];
    const float* br = (const float*)d_in[bi + 3];
    const float* We = (const float*)d_in[bi + 4];
    const float* att = (const float*)d_in[bi + 5];
    const float* bo = (const float*)d_in[bi + 6];
    const float* gg = (const float*)d_in[bi + 7];
    const float* be = (const float*)d_in[bi + 8];

    prep_w<<<128, 256, 0, stream>>>(Wl, Wr, wt1, wt2);
    gemm_mfma_dual<<<(N + 127) / 128, 512, 0, stream>>>(xb, wt1, wt2, bl, br, xlh, xr, N);
    int nGrid = (N + 3) / 4;
    const int* srcK = PERM_OK ? src_perm : src;
    if (l < 2) {
      if (PERM_OK)
        fused_gat<4, true, true><<<nGrid, 256, 0, stream>>>(
            xlh, xr, ea16, We, att, rowptr, eperm, srcK, nodeorder, bo, gg, be,
            nullptr, xb, N, E);
      else
        fused_gat<4, true, false><<<nGrid, 256, 0, stream>>>(
            xlh, xr, ea16, We, att, rowptr, eperm, srcK, nodeorder, bo, gg, be,
            nullptr, xb, N, E);
    } else {
      if (PERM_OK)
        fused_gat<1, false, true><<<nGrid, 256, 0, stream>>>(
            xlh, xr, ea16, We, att, rowptr, eperm, srcK, nodeorder, bo, gg, be,
            (float*)d_out, nullptr, N, E);
      else
        fused_gat<1, false, false><<<nGrid, 256, 0, stream>>>(
            xlh, xr, ea16, We, att, rowptr, eperm, srcK, nodeorder, bo, gg, be,
            (float*)d_out, nullptr, N, E);
    }
  }
}

// Round 11
// 899.801 us; speedup vs baseline: 1.0430x; 1.0430x over previous
//
#include <hip/hip_runtime.h>
#include <hip/hip_fp16.h>

// ---------------------------------------------------------------------------
// GATv2 3-layer GNN encoder. N=50000 nodes, E=800000 edges, dims 128.
// CSR build (multi-block scan) + degree-sort + fp16 edge-stream permute;
// per layer: [prep_w, MFMA dual GEMM, fused edge-score (fdot2) + softmax +
// aggregate + bias + LN + ReLU]. fused: 1 wave (64 thr) per node,
// __launch_bounds__(64,4) -> 128 VGPR budget so 8-edge ILP stays in regs.
// ---------------------------------------------------------------------------

typedef __attribute__((ext_vector_type(8))) short bf16x8;
typedef __attribute__((ext_vector_type(4))) float f32x4;
typedef __fp16 h2 __attribute__((ext_vector_type(2)));

__device__ inline ushort f2bf(float f) {
  unsigned u = __float_as_uint(f);
  u += 0x7FFF + ((u >> 16) & 1);
  return (ushort)(u >> 16);
}

__device__ inline ushort f2h(float f) {
  __half h = __float2half(f);
  return *(ushort*)&h;
}

__device__ inline uint pk2(float a, float b) {
#if __has_builtin(__builtin_amdgcn_cvt_pkrtz)
  h2 r = __builtin_amdgcn_cvt_pkrtz(a, b);
  return *(uint*)&r;
#else
  return (uint)f2h(a) | ((uint)f2h(b) << 16);
#endif
}

__device__ inline float fdot2(uint a, uint b, float c) {
#if __has_builtin(__builtin_amdgcn_fdot2)
  return __builtin_amdgcn_fdot2(*(h2*)&a, *(h2*)&b, c, false);
#else
  float2 fa = __half22float2(*(__half2*)&a);
  float2 fb = __half22float2(*(__half2*)&b);
  return c + fa.x * fb.x + fa.y * fb.y;
#endif
}

__device__ inline uint swz_add(uint p, int o) {
  int q = __shfl_xor(*(int*)&p, o);
  __half2 r = __hadd2(*(__half2*)&p, *(__half2*)&q);
  return *(uint*)&r;
}

// ---------------- CSR build ----------------

__global__ __launch_bounds__(256) void hist_kernel(const int* __restrict__ dst,
                                                   int* __restrict__ deg, int nE) {
  int i = blockIdx.x * 256 + threadIdx.x;
  if (i < nE) atomicAdd(&deg[dst[i]], 1);
}

__global__ __launch_bounds__(1024) void scan_blocks(const int* __restrict__ deg,
                                                    int* __restrict__ rowptr,
                                                    int* __restrict__ bsum, int n) {
  __shared__ int wsum[16];
  __shared__ int wbase[16];
  int tid = threadIdx.x, wid = tid >> 6, lane = tid & 63;
  int i = blockIdx.x * 1024 + tid;
  int v = (i < n) ? deg[i] : 0;
#pragma unroll
  for (int o = 1; o < 64; o <<= 1) {
    int t = __shfl_up(v, o);
    if (lane >= o) v += t;
  }
  if (lane == 63) wsum[wid] = v;
  __syncthreads();
  if (tid < 16) {
    int s = wsum[tid];
#pragma unroll
    for (int o = 1; o < 16; o <<= 1) {
      int t = __shfl_up(s, o);
      if (tid >= o) s += t;
    }
    wbase[tid] = s;
  }
  __syncthreads();
  int base = (wid > 0) ? wbase[wid - 1] : 0;
  if (i < n) rowptr[i + 1] = base + v;
  if (tid == 1023) bsum[blockIdx.x] = wbase[15];
}

__global__ __launch_bounds__(64) void scan_carry(int* __restrict__ bsum, int nb) {
  int lane = threadIdx.x;
  int carry = 0;
  for (int base = 0; base < nb; base += 64) {
    int i = base + lane;
    int v = (i < nb) ? bsum[i] : 0;
    int inc = v;
#pragma unroll
    for (int o = 1; o < 64; o <<= 1) {
      int t = __shfl_up(inc, o);
      if (lane >= o) inc += t;
    }
    if (i < nb) bsum[i] = carry + inc - v;
    carry += __shfl(inc, 63);
  }
}

__global__ __launch_bounds__(1024) void scan_apply(int* __restrict__ rowptr,
                                                   const int* __restrict__ bsum, int n) {
  int i = blockIdx.x * 1024 + threadIdx.x;
  if (i < n) rowptr[i + 1] += bsum[blockIdx.x];
  if (i == 0) rowptr[0] = 0;
}

__global__ __launch_bounds__(256) void scatter_kernel(const int* __restrict__ dst,
                                                      const int* __restrict__ rowptr,
                                                      int* __restrict__ cnt,
                                                      int* __restrict__ eperm, int nE) {
  int i = blockIdx.x * 256 + threadIdx.x;
  if (i < nE) {
    int d = dst[i];
    int p = atomicAdd(&cnt[d], 1);
    eperm[rowptr[d] + p] = i;
  }
}

__global__ __launch_bounds__(256) void deg_hist(const int* __restrict__ rowptr,
                                                int* __restrict__ dh, int nN) {
  int i = blockIdx.x * 256 + threadIdx.x;
  if (i < nN) {
    int dg = min(rowptr[i + 1] - rowptr[i], 255);
    atomicAdd(&dh[dg], 1);
  }
}

__global__ __launch_bounds__(256) void deg_scan(const int* __restrict__ dh,
                                                int* __restrict__ dbase) {
  __shared__ int s[256];
  int t = threadIdx.x;
  s[t] = dh[t];
  __syncthreads();
  for (int ofs = 1; ofs < 256; ofs <<= 1) {
    int v = (t >= ofs) ? s[t - ofs] : 0;
    __syncthreads();
    s[t] += v;
    __syncthreads();
  }
  dbase[t] = s[255] - s[t];
}

__global__ __launch_bounds__(256) void deg_scatter(const int* __restrict__ rowptr,
                                                   const int* __restrict__ dbase,
                                                   int* __restrict__ dcnt,
                                                   int* __restrict__ nodeorder, int nN) {
  int i = blockIdx.x * 256 + threadIdx.x;
  if (i < nN) {
    int dg = min(rowptr[i + 1] - rowptr[i], 255);
    int p = atomicAdd(&dcnt[dg], 1);
    nodeorder[dbase[dg] + p] = i;
  }
}

// ---------------- edge stream prep ----------------

__global__ __launch_bounds__(256) void convert_ea(const float* __restrict__ ea,
                                                  ushort* __restrict__ tmp, int n8) {
  int i = blockIdx.x * 256 + threadIdx.x;
  if (i < n8) {
    float4 a = ((const float4*)ea)[i * 2];
    float4 b = ((const float4*)ea)[i * 2 + 1];
    union { ushort r[8]; uint4 v; } u;
    u.r[0] = f2h(a.x); u.r[1] = f2h(a.y); u.r[2] = f2h(a.z); u.r[3] = f2h(a.w);
    u.r[4] = f2h(b.x); u.r[5] = f2h(b.y); u.r[6] = f2h(b.z); u.r[7] = f2h(b.w);
    ((uint4*)tmp)[i] = u.v;
  }
}

__global__ __launch_bounds__(256) void permute_ea(const ushort* __restrict__ tmp,
                                                  const int* __restrict__ eperm,
                                                  const int* __restrict__ src,
                                                  ushort* __restrict__ ea16,
                                                  int* __restrict__ src_perm, int nE) {
  int t = blockIdx.x * 256 + threadIdx.x;
  int j = t >> 2, part = t & 3;
  if (j < nE) {
    int e = eperm[j];
    ((uint4*)&ea16[(size_t)j * 32])[part] =
        ((const uint4*)&tmp[(size_t)e * 32])[part];
    if (part == 0) src_perm[j] = src[e];
  }
}

template <bool PERM>
__global__ __launch_bounds__(256) void prep_edges_h(const float* __restrict__ ea,
                                                    const int* __restrict__ eperm,
                                                    const int* __restrict__ src,
                                                    ushort* __restrict__ ea16,
                                                    int* __restrict__ src_perm, int nE) {
  int t = blockIdx.x * 256 + threadIdx.x;
  int j = t >> 3, ch = (t & 7) << 2;
  if (j < nE) {
    int e = PERM ? eperm[j] : j;
    float4 v = *(const float4*)&ea[(size_t)e * 32 + ch];
    ushort4 h;
    h.x = f2h(v.x); h.y = f2h(v.y); h.z = f2h(v.z); h.w = f2h(v.w);
    *(ushort4*)&ea16[(size_t)j * 32 + ch] = h;
    if (PERM && ch == 0) src_perm[j] = src[e];
  }
}

// ---------------- bf16 prep ----------------

__global__ __launch_bounds__(256) void convert_x(const float* __restrict__ x,
                                                 ushort* __restrict__ xb, int n8) {
  int i = blockIdx.x * 256 + threadIdx.x;
  if (i < n8) {
    float4 a = ((const float4*)x)[i * 2];
    float4 b = ((const float4*)x)[i * 2 + 1];
    union { ushort r[8]; uint4 v; } u;
    u.r[0] = f2bf(a.x); u.r[1] = f2bf(a.y); u.r[2] = f2bf(a.z); u.r[3] = f2bf(a.w);
    u.r[4] = f2bf(b.x); u.r[5] = f2bf(b.y); u.r[6] = f2bf(b.z); u.r[7] = f2bf(b.w);
    ((uint4*)xb)[i] = u.v;
  }
}

__global__ __launch_bounds__(256) void prep_w(const float* __restrict__ Wl,
                                              const float* __restrict__ Wr,
                                              ushort* __restrict__ wt1,
                                              ushort* __restrict__ wt2) {
  int idx = blockIdx.x * 256 + threadIdx.x;
  int mat = idx >> 14, rem = idx & 16383;
  int n = rem >> 7, k = rem & 127;
  const float* W = mat ? Wr : Wl;
  ushort* wt = mat ? wt2 : wt1;
  wt[n * 128 + k] = f2bf(W[(size_t)k * 128 + n]);
}

// ---------------- MFMA dual GEMM ----------------
#define XPAD 136

__device__ inline bf16x8 load_frag(const ushort* p) {
  union { bf16x8 v; unsigned long long q[2]; } u;
  u.q[0] = *(const unsigned long long*)p;
  u.q[1] = *(const unsigned long long*)(p + 16);
  return u.v;
}

__global__ __launch_bounds__(512) void gemm_mfma_dual(
    const ushort* __restrict__ xb, const ushort* __restrict__ wt1,
    const ushort* __restrict__ wt2, const float* __restrict__ b1,
    const float* __restrict__ b2, ushort* __restrict__ xlh,
    float* __restrict__ y2, int nrows) {
  __shared__ ushort Xs[128 * XPAD];
  __shared__ ushort Ws[128 * XPAD];
  const int tid = threadIdx.x;
  const int r0 = blockIdx.x * 128;

#pragma unroll
  for (int i = 0; i < 4; ++i) {
    int c = tid + i * 512;
    int row = c >> 4, kc = (c & 15) << 3;
    int gr = min(r0 + row, nrows - 1);
    *(uint4*)&Xs[row * XPAD + kc] = *(const uint4*)&xb[(size_t)gr * 128 + kc];
    *(uint4*)&Ws[row * XPAD + kc] = *(const uint4*)&wt1[row * 128 + kc];
  }
  __syncthreads();

  const int wid = tid >> 6, lane = tid & 63;
  const int lr = lane & 15, lg = lane >> 4;
  const int RB = (wid & 3) * 32, CB = (wid >> 2) * 64;

  f32x4 acc1[2][4] = {{{0.f}}};
  f32x4 acc2[2][4] = {{{0.f}}};

#pragma unroll
  for (int ks = 0; ks < 4; ++ks) {
    const int kb = ks * 32 + lg * 4;
    bf16x8 a0 = load_frag(&Xs[(RB + lr) * XPAD + kb]);
    bf16x8 a1 = load_frag(&Xs[(RB + 16 + lr) * XPAD + kb]);
#pragma unroll
    for (int nt = 0; nt < 4; ++nt) {
      const int n = CB + nt * 16 + lr;
      bf16x8 bw = load_frag(&Ws[n * XPAD + kb]);
      acc1[0][nt] = __builtin_amdgcn_mfma_f32_16x16x32_bf16(a0, bw, acc1[0][nt], 0, 0, 0);
      acc1[1][nt] = __builtin_amdgcn_mfma_f32_16x16x32_bf16(a1, bw, acc1[1][nt], 0, 0, 0);
    }
  }
  __syncthreads();
#pragma unroll
  for (int i = 0; i < 4; ++i) {
    int c = tid + i * 512;
    int row = c >> 4, kc = (c & 15) << 3;
    *(uint4*)&Ws[row * XPAD + kc] = *(const uint4*)&wt2[row * 128 + kc];
  }
  __syncthreads();
#pragma unroll
  for (int ks = 0; ks < 4; ++ks) {
    const int kb = ks * 32 + lg * 4;
    bf16x8 a0 = load_frag(&Xs[(RB + lr) * XPAD + kb]);
    bf16x8 a1 = load_frag(&Xs[(RB + 16 + lr) * XPAD + kb]);
#pragma unroll
    for (int nt = 0; nt < 4; ++nt) {
      const int n = CB + nt * 16 + lr;
      bf16x8 bw = load_frag(&Ws[n * XPAD + kb]);
      acc2[0][nt] = __builtin_amdgcn_mfma_f32_16x16x32_bf16(a0, bw, acc2[0][nt], 0, 0, 0);
      acc2[1][nt] = __builtin_amdgcn_mfma_f32_16x16x32_bf16(a1, bw, acc2[1][nt], 0, 0, 0);
    }
  }

#pragma unroll
  for (int nt = 0; nt < 4; ++nt) {
    const int col = CB + nt * 16 + lr;
    const float bb1 = b1[col], bb2 = b2[col];
    const int hoff = ((col & 63) << 1) | (col >> 6);
#pragma unroll
    for (int mt = 0; mt < 2; ++mt) {
#pragma unroll
      for (int r = 0; r < 4; ++r) {
        int gr = r0 + RB + mt * 16 + lg * 4 + r;
        if (gr < nrows) {
          xlh[(size_t)gr * 128 + hoff] = f2h(acc1[mt][nt][r] + bb1);
          y2[(size_t)gr * 128 + col] = acc2[mt][nt][r] + bb2;
        }
      }
    }
  }
}

// ---------------- fused GATv2 layer ----------------
// ONE wave per 64-thread block; __launch_bounds__(64,4) -> 128 VGPR budget.
// Thread owns dims cL=lane, cH=lane+64. ea16 direct loads (uniform addr);
// 8 edges in flight, all ILP arrays register-resident. No LDS, no barriers.
template <int H, bool OB, bool PERM>
__global__ __launch_bounds__(64, 4) void fused_gat(const ushort* __restrict__ xlh,
                                                   const float* __restrict__ xr,
                                                   const ushort* __restrict__ ea16,
                                                   const float* __restrict__ We,
                                                   const float* __restrict__ att,
                                                   const int* __restrict__ rowptr,
                                                   const int* __restrict__ eperm,
                                                   const int* __restrict__ src,
                                                   const int* __restrict__ nodeorder,
                                                   const float* __restrict__ bias,
                                                   const float* __restrict__ gam,
                                                   const float* __restrict__ bet,
                                                   float* __restrict__ out,
                                                   ushort* __restrict__ outb, int nN) {
  const int lane = threadIdx.x;
  const int bn = blockIdx.x;
  if (bn >= nN) return;
  const int n = __builtin_amdgcn_readfirstlane(nodeorder[bn]);
  const int rb = __builtin_amdgcn_readfirstlane(rowptr[n]);
  const int re = __builtin_amdgcn_readfirstlane(rowptr[n + 1]);
  const int cL = lane, cH = lane + 64;
  const uint* __restrict__ xlw = (const uint*)xlh;
  const uint* __restrict__ eaw = (const uint*)ea16;

  uint WcLp[16], WcHp[16];
#pragma unroll
  for (int k = 0; k < 16; ++k) {
    WcLp[k] = pk2(We[(2 * k) * 128 + cL], We[(2 * k + 1) * 128 + cL]);
    WcHp[k] = pk2(We[(2 * k) * 128 + cH], We[(2 * k + 1) * 128 + cH]);
  }
#pragma unroll
  for (int k = 0; k < 16; ++k) {
    asm volatile("" : "+v"(WcLp[k]), "+v"(WcHp[k]));
  }
  const float attL = att[cL] * 1.44269504088896f;
  const float attH = att[cH] * 1.44269504088896f;
  const float xrL = xr[(size_t)n * 128 + cL];
  const float xrH = xr[(size_t)n * 128 + cH];

  float dL = 0.f, dH = 0.f, accL = 0.f, accH = 0.f;

  for (int b0 = rb; b0 < re; b0 += 64) {
    const int cnt = min(64, re - b0);
    const int jj = b0 + lane;
    int sv, ev = 0;
    if (PERM) {
      sv = (jj < re) ? src[jj] : 0;
    } else {
      ev = (jj < re) ? eperm[jj] : 0;
      sv = (jj < re) ? src[ev] : 0;
    }

    for (int i = 0; i < cnt; i += 8) {
      uint uu[8];
      float fx[8], fy[8], pl[8], ph[8];
#pragma unroll
      for (int j = 0; j < 8; ++j) {  // issue all gathers first
        int ij = min(i + j, cnt - 1);
        int sj = __builtin_amdgcn_readlane(sv, ij);
        uu[j] = xlw[(size_t)sj * 64 + lane];
      }
#pragma unroll
      for (int j = 0; j < 8; ++j) {
        int ij = min(i + j, cnt - 1);
        size_t ro;
        if (PERM) {
          ro = (size_t)(b0 + ij) * 16;  // sequential fp16 rows
        } else {
          ro = (size_t)__builtin_amdgcn_readlane(ev, ij) * 16;
        }
        const uint4* ep = (const uint4*)(eaw + ro);  // uniform addr
        uint4 q0 = ep[0], q1 = ep[1], q2 = ep[2], q3 = ep[3];
        float2 f = __half22float2(*(__half2*)&uu[j]);
        float mL = f.x + xrL, mH = f.y + xrH;
        mL = fdot2(q0.x, WcLp[0], mL);  mH = fdot2(q0.x, WcHp[0], mH);
        mL = fdot2(q0.y, WcLp[1], mL);  mH = fdot2(q0.y, WcHp[1], mH);
        mL = fdot2(q0.z, WcLp[2], mL);  mH = fdot2(q0.z, WcHp[2], mH);
        mL = fdot2(q0.w, WcLp[3], mL);  mH = fdot2(q0.w, WcHp[3], mH);
        mL = fdot2(q1.x, WcLp[4], mL);  mH = fdot2(q1.x, WcHp[4], mH);
        mL = fdot2(q1.y, WcLp[5], mL);  mH = fdot2(q1.y, WcHp[5], mH);
        mL = fdot2(q1.z, WcLp[6], mL);  mH = fdot2(q1.z, WcHp[6], mH);
        mL = fdot2(q1.w, WcLp[7], mL);  mH = fdot2(q1.w, WcHp[7], mH);
        mL = fdot2(q2.x, WcLp[8], mL);  mH = fdot2(q2.x, WcHp[8], mH);
        mL = fdot2(q2.y, WcLp[9], mL);  mH = fdot2(q2.y, WcHp[9], mH);
        mL = fdot2(q2.z, WcLp[10], mL); mH = fdot2(q2.z, WcHp[10], mH);
        mL = fdot2(q2.w, WcLp[11], mL); mH = fdot2(q2.w, WcHp[11], mH);
        mL = fdot2(q3.x, WcLp[12], mL); mH = fdot2(q3.x, WcHp[12], mH);
        mL = fdot2(q3.y, WcLp[13], mL); mH = fdot2(q3.y, WcHp[13], mH);
        mL = fdot2(q3.z, WcLp[14], mL); mH = fdot2(q3.z, WcHp[14], mH);
        mL = fdot2(q3.w, WcLp[15], mL); mH = fdot2(q3.w, WcHp[15], mH);
        fx[j] = f.x;
        fy[j] = f.y;
        pl[j] = fmaxf(mL, 0.2f * mL) * attL;
        ph[j] = fmaxf(mH, 0.2f * mH) * attH;
      }
#pragma unroll
      for (int pr = 0; pr < 4; ++pr) {
        const int a = 2 * pr, b = 2 * pr + 1;
        uint packL, packH;
        if (H == 4) {
          packL = pk2(pl[a], pl[b]);
          packH = pk2(ph[a], ph[b]);
#pragma unroll
          for (int o = 16; o >= 1; o >>= 1) {
            packL = swz_add(packL, o);
            packH = swz_add(packH, o);
          }
        } else {
          packL = pk2(pl[a] + ph[a], pl[b] + ph[b]);
#pragma unroll
          for (int o = 32; o >= 1; o >>= 1) {
            packL = swz_add(packL, o);
          }
          packH = packL;
        }
        float2 sL = __half22float2(*(__half2*)&packL);
        float2 sH = __half22float2(*(__half2*)&packH);
        float wLa = exp2f(fminf(sL.x, 115.f));
        float wLb = exp2f(fminf(sL.y, 115.f));
        float wHa = exp2f(fminf(sH.x, 115.f));
        float wHb = exp2f(fminf(sH.y, 115.f));
        if (i + a >= cnt) { wLa = 0.f; wHa = 0.f; }
        if (i + b >= cnt) { wLb = 0.f; wHb = 0.f; }
        dL += wLa + wLb;
        dH += wHa + wHb;
        accL += wLa * fx[a] + wLb * fx[b];
        accH += wHa * fy[a] + wHb * fy[b];
      }
    }
  }

  const float rdL = (dL > 0.f) ? 1.f / dL : 0.f;
  const float rdH = (dH > 0.f) ? 1.f / dH : 0.f;
  float y0 = accL * rdL + bias[cL];
  float y1 = accH * rdH + bias[cH];

  float sm = y0 + y1, sq = y0 * y0 + y1 * y1;
#pragma unroll
  for (int o = 32; o >= 1; o >>= 1) {
    sm += __shfl_xor(sm, o);
    sq += __shfl_xor(sq, o);
  }
  const float mu = sm * (1.f / 128.f);
  const float var = sq * (1.f / 128.f) - mu * mu;
  const float rstd = rsqrtf(var + 1e-5f);
  const float o0 = fmaxf((y0 - mu) * rstd * gam[cL] + bet[cL], 0.f);
  const float o1 = fmaxf((y1 - mu) * rstd * gam[cH] + bet[cH], 0.f);
  if (OB) {
    outb[(size_t)n * 128 + cL] = f2bf(o0);
    outb[(size_t)n * 128 + cH] = f2bf(o1);
  } else {
    out[(size_t)n * 128 + cL] = o0;
    out[(size_t)n * 128 + cH] = o1;
  }
}

extern "C" void kernel_launch(void* const* d_in, const int* in_sizes, int n_in,
                              void* d_out, int out_size, void* d_ws, size_t ws_size,
                              hipStream_t stream) {
  const float* x = (const float*)d_in[0];
  const float* ea = (const float*)d_in[1];
  const int* src = (const int*)d_in[2];
  const int* dst = (const int*)d_in[3];
  const int N = in_sizes[0] / 128;
  const int E = in_sizes[2];

  char* w = (char*)d_ws;
  auto alloc = [&](size_t bytes) {
    char* p = w;
    w += (bytes + 255) & ~(size_t)255;
    return p;
  };
  ushort* xlh = (ushort*)alloc((size_t)N * 128 * 2);
  float* xr = (float*)alloc((size_t)N * 128 * 4);
  ushort* xb = (ushort*)alloc((size_t)N * 128 * 2);
  ushort* wt1 = (ushort*)alloc(128 * 128 * 2);
  ushort* wt2 = (ushort*)alloc(128 * 128 * 2);
  int* eperm = (int*)alloc((size_t)E * 4);
  int* rowptr = (int*)alloc((size_t)(N + 1) * 4);
  int* deg = (int*)alloc((size_t)N * 4);
  int* cnt = (int*)alloc((size_t)N * 4);
  int* nodeorder = (int*)alloc((size_t)N * 4);
  int* dh = (int*)alloc(256 * 4);
  int* dbase = (int*)alloc(256 * 4);
  int* dcnt = (int*)alloc(256 * 4);
  int* bsum = (int*)alloc(1024 * 4);
  ushort* ea16 = (ushort*)alloc((size_t)E * 32 * 2);
  size_t used = (size_t)(w - (char*)d_ws);
  const bool PERM_OK = (used + (size_t)E * 4 + 256 <= ws_size);
  int* src_perm = nullptr;
  if (PERM_OK) src_perm = (int*)alloc((size_t)E * 4);
  used = (size_t)(w - (char*)d_ws);
  const bool SPLIT_OK = PERM_OK && (used + (size_t)E * 32 * 2 + 256 <= ws_size);
  ushort* tmp16 = nullptr;
  if (SPLIT_OK) tmp16 = (ushort*)alloc((size_t)E * 32 * 2);

  hipMemsetAsync(deg, 0, (size_t)N * 4, stream);
  hipMemsetAsync(cnt, 0, (size_t)N * 4, stream);
  hipMemsetAsync(dh, 0, 256 * 4, stream);
  hipMemsetAsync(dcnt, 0, 256 * 4, stream);
  hist_kernel<<<(E + 255) / 256, 256, 0, stream>>>(dst, deg, E);
  int nb = (N + 1023) / 1024;
  scan_blocks<<<nb, 1024, 0, stream>>>(deg, rowptr, bsum, N);
  scan_carry<<<1, 64, 0, stream>>>(bsum, nb);
  scan_apply<<<nb, 1024, 0, stream>>>(rowptr, bsum, N);
  scatter_kernel<<<(E + 255) / 256, 256, 0, stream>>>(dst, rowptr, cnt, eperm, E);
  deg_hist<<<(N + 255) / 256, 256, 0, stream>>>(rowptr, dh, N);
  deg_scan<<<1, 256, 0, stream>>>(dh, dbase);
  deg_scatter<<<(N + 255) / 256, 256, 0, stream>>>(rowptr, dbase, dcnt, nodeorder, N);

  if (SPLIT_OK) {
    convert_ea<<<(E * 4 + 255) / 256, 256, 0, stream>>>(ea, tmp16, E * 4);
    permute_ea<<<((size_t)E * 4 + 255) / 256, 256, 0, stream>>>(tmp16, eperm, src,
                                                                ea16, src_perm, E);
  } else if (PERM_OK) {
    prep_edges_h<true><<<((size_t)E * 8 + 255) / 256, 256, 0, stream>>>(
        ea, eperm, src, ea16, src_perm, E);
  } else {
    prep_edges_h<false><<<((size_t)E * 8 + 255) / 256, 256, 0, stream>>>(
        ea, eperm, src, ea16, nullptr, E);
  }

  int n8 = N * 128 / 8;
  convert_x<<<(n8 + 255) / 256, 256, 0, stream>>>(x, xb, n8);

  for (int l = 0; l < 3; ++l) {
    int bi = 4 + 9 * l;
    const float* Wl = (const float*)d_in[bi + 0];
    const float* bl = (const float*)d_in[bi + 1];
    const float* Wr = (const float*)d_in[bi + 2];
    const float* br = (const float*)d_in[bi + 3];
    const float* We = (const float*)d_in[bi + 4];
    const float* att = (const float*)d_in[bi + 5];
    const float* bo = (const float*)d_in[bi + 6];
    const float* gg = (const float*)d_in[bi + 7];
    const float* be = (const float*)d_in[bi + 8];

    prep_w<<<128, 256, 0, stream>>>(Wl, Wr, wt1, wt2);
    gemm_mfma_dual<<<(N + 127) / 128, 512, 0, stream>>>(xb, wt1, wt2, bl, br, xlh, xr, N);
    const int* srcK = PERM_OK ? src_perm : src;
    if (l < 2) {
      if (PERM_OK)
        fused_gat<4, true, true><<<N, 64, 0, stream>>>(
            xlh, xr, ea16, We, att, rowptr, eperm, srcK, nodeorder, bo, gg, be,
            nullptr, xb, N);
      else
        fused_gat<4, true, false><<<N, 64, 0, stream>>>(
            xlh, xr, ea16, We, att, rowptr, eperm, srcK, nodeorder, bo, gg, be,
            nullptr, xb, N);
    } else {
      if (PERM_OK)
        fused_gat<1, false, true><<<N, 64, 0, stream>>>(
            xlh, xr, ea16, We, att, rowptr, eperm, srcK, nodeorder, bo, gg, be,
            (float*)d_out, nullptr, N);
      else
        fused_gat<1, false, false><<<N, 64, 0, stream>>>(
            xlh, xr, ea16, We, att, rowptr, eperm, srcK, nodeorder, bo, gg, be,
            (float*)d_out, nullptr, N);
    }
  }
}

// Round 12
// 837.478 us; speedup vs baseline: 1.1206x; 1.0744x over previous
//
#include <hip/hip_runtime.h>
#include <hip/hip_fp16.h>

// ---------------------------------------------------------------------------
// GATv2 3-layer GNN encoder. N=50000 nodes, E=800000 edges, dims 128.
// CSR build + degree-sort + fp16 edge-stream permute (once); per layer:
// [prep_w (+We^T), MFMA dual GEMM (xlh fp16-interleaved + xr fp32), fused
// layer: per 16-edge tile the wave computes eproj = ea@We with 8 MFMAs
// (f16, fp32-acc), then score/softmax/aggregate/LN on the VALU].
// ---------------------------------------------------------------------------

typedef __attribute__((ext_vector_type(8))) short bf16x8;
typedef __attribute__((ext_vector_type(4))) float f32x4;
typedef __fp16 h2 __attribute__((ext_vector_type(2)));
typedef __fp16 h8 __attribute__((ext_vector_type(8)));

__device__ inline ushort f2bf(float f) {
  unsigned u = __float_as_uint(f);
  u += 0x7FFF + ((u >> 16) & 1);
  return (ushort)(u >> 16);
}

__device__ inline ushort f2h(float f) {
  __half h = __float2half(f);
  return *(ushort*)&h;
}

__device__ inline uint pk2(float a, float b) {
#if __has_builtin(__builtin_amdgcn_cvt_pkrtz)
  h2 r = __builtin_amdgcn_cvt_pkrtz(a, b);
  return *(uint*)&r;
#else
  return (uint)f2h(a) | ((uint)f2h(b) << 16);
#endif
}

__device__ inline uint swz_add(uint p, int o) {  // packed-f16 butterfly step
  int q = __shfl_xor(*(int*)&p, o);
  __half2 r = __hadd2(*(__half2*)&p, *(__half2*)&q);
  return *(uint*)&r;
}

// ---------------- CSR build ----------------

__global__ __launch_bounds__(256) void hist_kernel(const int* __restrict__ dst,
                                                   int* __restrict__ deg, int nE) {
  int i = blockIdx.x * 256 + threadIdx.x;
  if (i < nE) atomicAdd(&deg[dst[i]], 1);
}

__global__ __launch_bounds__(1024) void scan_blocks(const int* __restrict__ deg,
                                                    int* __restrict__ rowptr,
                                                    int* __restrict__ bsum, int n) {
  __shared__ int wsum[16];
  __shared__ int wbase[16];
  int tid = threadIdx.x, wid = tid >> 6, lane = tid & 63;
  int i = blockIdx.x * 1024 + tid;
  int v = (i < n) ? deg[i] : 0;
#pragma unroll
  for (int o = 1; o < 64; o <<= 1) {
    int t = __shfl_up(v, o);
    if (lane >= o) v += t;
  }
  if (lane == 63) wsum[wid] = v;
  __syncthreads();
  if (tid < 16) {
    int s = wsum[tid];
#pragma unroll
    for (int o = 1; o < 16; o <<= 1) {
      int t = __shfl_up(s, o);
      if (tid >= o) s += t;
    }
    wbase[tid] = s;
  }
  __syncthreads();
  int base = (wid > 0) ? wbase[wid - 1] : 0;
  if (i < n) rowptr[i + 1] = base + v;
  if (tid == 1023) bsum[blockIdx.x] = wbase[15];
}

__global__ __launch_bounds__(64) void scan_carry(int* __restrict__ bsum, int nb) {
  int lane = threadIdx.x;
  int carry = 0;
  for (int base = 0; base < nb; base += 64) {
    int i = base + lane;
    int v = (i < nb) ? bsum[i] : 0;
    int inc = v;
#pragma unroll
    for (int o = 1; o < 64; o <<= 1) {
      int t = __shfl_up(inc, o);
      if (lane >= o) inc += t;
    }
    if (i < nb) bsum[i] = carry + inc - v;
    carry += __shfl(inc, 63);
  }
}

__global__ __launch_bounds__(1024) void scan_apply(int* __restrict__ rowptr,
                                                   const int* __restrict__ bsum, int n) {
  int i = blockIdx.x * 1024 + threadIdx.x;
  if (i < n) rowptr[i + 1] += bsum[blockIdx.x];
  if (i == 0) rowptr[0] = 0;
}

__global__ __launch_bounds__(256) void scatter_kernel(const int* __restrict__ dst,
                                                      const int* __restrict__ rowptr,
                                                      int* __restrict__ cnt,
                                                      int* __restrict__ eperm, int nE) {
  int i = blockIdx.x * 256 + threadIdx.x;
  if (i < nE) {
    int d = dst[i];
    int p = atomicAdd(&cnt[d], 1);
    eperm[rowptr[d] + p] = i;
  }
}

__global__ __launch_bounds__(256) void deg_hist(const int* __restrict__ rowptr,
                                                int* __restrict__ dh, int nN) {
  int i = blockIdx.x * 256 + threadIdx.x;
  if (i < nN) {
    int dg = min(rowptr[i + 1] - rowptr[i], 255);
    atomicAdd(&dh[dg], 1);
  }
}

__global__ __launch_bounds__(256) void deg_scan(const int* __restrict__ dh,
                                                int* __restrict__ dbase) {
  __shared__ int s[256];
  int t = threadIdx.x;
  s[t] = dh[t];
  __syncthreads();
  for (int ofs = 1; ofs < 256; ofs <<= 1) {
    int v = (t >= ofs) ? s[t - ofs] : 0;
    __syncthreads();
    s[t] += v;
    __syncthreads();
  }
  dbase[t] = s[255] - s[t];
}

__global__ __launch_bounds__(256) void deg_scatter(const int* __restrict__ rowptr,
                                                   const int* __restrict__ dbase,
                                                   int* __restrict__ dcnt,
                                                   int* __restrict__ nodeorder, int nN) {
  int i = blockIdx.x * 256 + threadIdx.x;
  if (i < nN) {
    int dg = min(rowptr[i + 1] - rowptr[i], 255);
    int p = atomicAdd(&dcnt[dg], 1);
    nodeorder[dbase[dg] + p] = i;
  }
}

// ---------------- edge stream prep ----------------

__global__ __launch_bounds__(256) void convert_ea(const float* __restrict__ ea,
                                                  ushort* __restrict__ tmp, int n8) {
  int i = blockIdx.x * 256 + threadIdx.x;
  if (i < n8) {
    float4 a = ((const float4*)ea)[i * 2];
    float4 b = ((const float4*)ea)[i * 2 + 1];
    union { ushort r[8]; uint4 v; } u;
    u.r[0] = f2h(a.x); u.r[1] = f2h(a.y); u.r[2] = f2h(a.z); u.r[3] = f2h(a.w);
    u.r[4] = f2h(b.x); u.r[5] = f2h(b.y); u.r[6] = f2h(b.z); u.r[7] = f2h(b.w);
    ((uint4*)tmp)[i] = u.v;
  }
}

__global__ __launch_bounds__(256) void permute_ea(const ushort* __restrict__ tmp,
                                                  const int* __restrict__ eperm,
                                                  const int* __restrict__ src,
                                                  ushort* __restrict__ ea16,
                                                  int* __restrict__ src_perm, int nE) {
  int t = blockIdx.x * 256 + threadIdx.x;
  int j = t >> 2, part = t & 3;
  if (j < nE) {
    int e = eperm[j];
    ((uint4*)&ea16[(size_t)j * 32])[part] =
        ((const uint4*)&tmp[(size_t)e * 32])[part];
    if (part == 0) src_perm[j] = src[e];
  }
}

__global__ __launch_bounds__(256) void prep_edges_h(const float* __restrict__ ea,
                                                    const int* __restrict__ eperm,
                                                    const int* __restrict__ src,
                                                    ushort* __restrict__ ea16,
                                                    int* __restrict__ src_perm, int nE) {
  int t = blockIdx.x * 256 + threadIdx.x;
  int j = t >> 3, ch = (t & 7) << 2;
  if (j < nE) {
    int e = eperm[j];
    float4 v = *(const float4*)&ea[(size_t)e * 32 + ch];
    ushort4 h;
    h.x = f2h(v.x); h.y = f2h(v.y); h.z = f2h(v.z); h.w = f2h(v.w);
    *(ushort4*)&ea16[(size_t)j * 32 + ch] = h;
    if (ch == 0) src_perm[j] = src[e];
  }
}

// ---------------- weight prep ----------------

__global__ __launch_bounds__(256) void convert_x(const float* __restrict__ x,
                                                 ushort* __restrict__ xb, int n8) {
  int i = blockIdx.x * 256 + threadIdx.x;
  if (i < n8) {
    float4 a = ((const float4*)x)[i * 2];
    float4 b = ((const float4*)x)[i * 2 + 1];
    union { ushort r[8]; uint4 v; } u;
    u.r[0] = f2bf(a.x); u.r[1] = f2bf(a.y); u.r[2] = f2bf(a.z); u.r[3] = f2bf(a.w);
    u.r[4] = f2bf(b.x); u.r[5] = f2bf(b.y); u.r[6] = f2bf(b.z); u.r[7] = f2bf(b.w);
    ((uint4*)xb)[i] = u.v;
  }
}

__global__ __launch_bounds__(256) void prep_w(const float* __restrict__ Wl,
                                              const float* __restrict__ Wr,
                                              ushort* __restrict__ wt1,
                                              ushort* __restrict__ wt2) {
  int idx = blockIdx.x * 256 + threadIdx.x;
  int mat = idx >> 14, rem = idx & 16383;
  int n = rem >> 7, k = rem & 127;
  const float* W = mat ? Wr : Wl;
  ushort* wt = mat ? wt2 : wt1;
  wt[n * 128 + k] = f2bf(W[(size_t)k * 128 + n]);
}

// weh[n][k] = fp16(We[k][n]), n<128, k<32
__global__ __launch_bounds__(256) void prep_we(const float* __restrict__ We,
                                               ushort* __restrict__ weh) {
  int idx = blockIdx.x * 256 + threadIdx.x;
  if (idx < 4096) {
    int n = idx >> 5, k = idx & 31;
    weh[n * 32 + k] = f2h(We[(size_t)k * 128 + n]);
  }
}

// ---------------- MFMA dual GEMM ----------------
#define XPAD 136

__device__ inline bf16x8 load_frag(const ushort* p) {
  union { bf16x8 v; unsigned long long q[2]; } u;
  u.q[0] = *(const unsigned long long*)p;
  u.q[1] = *(const unsigned long long*)(p + 16);
  return u.v;
}

__global__ __launch_bounds__(512) void gemm_mfma_dual(
    const ushort* __restrict__ xb, const ushort* __restrict__ wt1,
    const ushort* __restrict__ wt2, const float* __restrict__ b1,
    const float* __restrict__ b2, ushort* __restrict__ xlh,
    float* __restrict__ y2, int nrows) {
  __shared__ ushort Xs[128 * XPAD];
  __shared__ ushort Ws[128 * XPAD];
  const int tid = threadIdx.x;
  const int r0 = blockIdx.x * 128;

#pragma unroll
  for (int i = 0; i < 4; ++i) {
    int c = tid + i * 512;
    int row = c >> 4, kc = (c & 15) << 3;
    int gr = min(r0 + row, nrows - 1);
    *(uint4*)&Xs[row * XPAD + kc] = *(const uint4*)&xb[(size_t)gr * 128 + kc];
    *(uint4*)&Ws[row * XPAD + kc] = *(const uint4*)&wt1[row * 128 + kc];
  }
  __syncthreads();

  const int wid = tid >> 6, lane = tid & 63;
  const int lr = lane & 15, lg = lane >> 4;
  const int RB = (wid & 3) * 32, CB = (wid >> 2) * 64;

  f32x4 acc1[2][4] = {{{0.f}}};
  f32x4 acc2[2][4] = {{{0.f}}};

#pragma unroll
  for (int ks = 0; ks < 4; ++ks) {
    const int kb = ks * 32 + lg * 4;
    bf16x8 a0 = load_frag(&Xs[(RB + lr) * XPAD + kb]);
    bf16x8 a1 = load_frag(&Xs[(RB + 16 + lr) * XPAD + kb]);
#pragma unroll
    for (int nt = 0; nt < 4; ++nt) {
      const int n = CB + nt * 16 + lr;
      bf16x8 bw = load_frag(&Ws[n * XPAD + kb]);
      acc1[0][nt] = __builtin_amdgcn_mfma_f32_16x16x32_bf16(a0, bw, acc1[0][nt], 0, 0, 0);
      acc1[1][nt] = __builtin_amdgcn_mfma_f32_16x16x32_bf16(a1, bw, acc1[1][nt], 0, 0, 0);
    }
  }
  __syncthreads();
#pragma unroll
  for (int i = 0; i < 4; ++i) {
    int c = tid + i * 512;
    int row = c >> 4, kc = (c & 15) << 3;
    *(uint4*)&Ws[row * XPAD + kc] = *(const uint4*)&wt2[row * 128 + kc];
  }
  __syncthreads();
#pragma unroll
  for (int ks = 0; ks < 4; ++ks) {
    const int kb = ks * 32 + lg * 4;
    bf16x8 a0 = load_frag(&Xs[(RB + lr) * XPAD + kb]);
    bf16x8 a1 = load_frag(&Xs[(RB + 16 + lr) * XPAD + kb]);
#pragma unroll
    for (int nt = 0; nt < 4; ++nt) {
      const int n = CB + nt * 16 + lr;
      bf16x8 bw = load_frag(&Ws[n * XPAD + kb]);
      acc2[0][nt] = __builtin_amdgcn_mfma_f32_16x16x32_bf16(a0, bw, acc2[0][nt], 0, 0, 0);
      acc2[1][nt] = __builtin_amdgcn_mfma_f32_16x16x32_bf16(a1, bw, acc2[1][nt], 0, 0, 0);
    }
  }

#pragma unroll
  for (int nt = 0; nt < 4; ++nt) {
    const int col = CB + nt * 16 + lr;
    const float bb1 = b1[col], bb2 = b2[col];
    const int hoff = ((col & 63) << 1) | (col >> 6);
#pragma unroll
    for (int mt = 0; mt < 2; ++mt) {
#pragma unroll
      for (int r = 0; r < 4; ++r) {
        int gr = r0 + RB + mt * 16 + lg * 4 + r;
        if (gr < nrows) {
          xlh[(size_t)gr * 128 + hoff] = f2h(acc1[mt][nt][r] + bb1);
          y2[(size_t)gr * 128 + col] = acc2[mt][nt][r] + bb2;
        }
      }
    }
  }
}

// ---------------- fused GATv2 layer (MFMA edge projection) ----------------
// ONE wave per node. Per 16-edge tile: A = ea16 rows (fp16), D[nt] =
// mfma_f32_16x16x32_f16(A, We^T[nt]) -> lane holds rows 4*lg..+3 (reg r),
// col 16*nt+lr. Scores: m = D + xr + xl (gathered fp16-interleaved dword),
// lrelu, att-dot; head sums via packed-f16 butterfly within 16-lane group.
// Cross-group combine at end (heads/acc), then softmax-normalize + LN.
template <int H, bool OB>
__global__ __launch_bounds__(64, 4) void fused_gat(
    const ushort* __restrict__ xlh, const float* __restrict__ xr,
    const ushort* __restrict__ ea16, const ushort* __restrict__ weh,
    const float* __restrict__ att, const int* __restrict__ rowptr,
    const int* __restrict__ src_perm, const int* __restrict__ nodeorder,
    const float* __restrict__ bias, const float* __restrict__ gam,
    const float* __restrict__ bet, float* __restrict__ out,
    ushort* __restrict__ outb, int nN) {
  const int l = threadIdx.x;
  const int lr = l & 15, lg = l >> 4;
  const int n = __builtin_amdgcn_readfirstlane(nodeorder[blockIdx.x]);
  const int rb = __builtin_amdgcn_readfirstlane(rowptr[n]);
  const int re = __builtin_amdgcn_readfirstlane(rowptr[n + 1]);
  const uint* __restrict__ xlw = (const uint*)xlh;

  // We^T fragments: col n = nt*16+lr, k = 4*lg + (j&3) + 16*(j>>2)
  unsigned long long bq[16];
#pragma unroll
  for (int nt = 0; nt < 8; ++nt) {
    const ushort* p = weh + (size_t)(nt * 16 + lr) * 32 + 4 * lg;
    bq[2 * nt] = *(const unsigned long long*)p;
    bq[2 * nt + 1] = *(const unsigned long long*)(p + 16);
  }
#pragma unroll
  for (int i = 0; i < 16; ++i) asm volatile("" : "+v"(bq[i]));  // pin

  float attv[8], xrv[8];
#pragma unroll
  for (int nt = 0; nt < 8; ++nt) {
    attv[nt] = att[lr + 16 * nt] * 1.44269504f;  // fold 1/ln2 -> exp2
    xrv[nt] = xr[(size_t)n * 128 + lr + 16 * nt];
  }

  float acc[8] = {0.f, 0.f, 0.f, 0.f, 0.f, 0.f, 0.f, 0.f};
  float d0 = 0.f, d1 = 0.f, d2 = 0.f, d3 = 0.f;

  for (int t0 = rb; t0 < re; t0 += 16) {
    // A-frag: row t0+lr (clamped), k = 4*lg+(j&3)+16*(j>>2)
    const int arow = min(t0 + lr, re - 1);
    union { unsigned long long q[2]; h8 v; } ua;
    const ushort* ap = ea16 + (size_t)arow * 32 + 4 * lg;
    ua.q[0] = *(const unsigned long long*)ap;
    ua.q[1] = *(const unsigned long long*)(ap + 16);

    // srcs + xl gathers for my group's rows (t0 + 4*lg + r)
    int sr_[4];
#pragma unroll
    for (int r = 0; r < 4; ++r)
      sr_[r] = src_perm[min(t0 + 4 * lg + r, re - 1)];
    uint u[4][4];
#pragma unroll
    for (int r = 0; r < 4; ++r) {
      const uint* xp = xlw + (size_t)sr_[r] * 64;
#pragma unroll
      for (int q = 0; q < 4; ++q) u[r][q] = xp[lr + 16 * q];
    }

    // eproj: 8 MFMAs
    f32x4 D[8];
#pragma unroll
    for (int nt = 0; nt < 8; ++nt) {
      union { unsigned long long q[2]; h8 v; } ub;
      ub.q[0] = bq[2 * nt];
      ub.q[1] = bq[2 * nt + 1];
      f32x4 z = {0.f, 0.f, 0.f, 0.f};
      D[nt] = __builtin_amdgcn_mfma_f32_16x16x32_f16(ua.v, ub.v, z, 0, 0, 0);
    }

    if (H == 4) {
#pragma unroll
      for (int r = 0; r < 4; ++r) {
        float xv[8];
#pragma unroll
        for (int q = 0; q < 4; ++q) {
          float2 f = __half22float2(*(__half2*)&u[r][q]);
          xv[q] = f.x;
          xv[q + 4] = f.y;
        }
        float p0 = 0.f, p1 = 0.f, p2 = 0.f, p3 = 0.f;
#pragma unroll
        for (int nt = 0; nt < 8; ++nt) {
          float m = D[nt][r] + xrv[nt] + xv[nt];
          m = fmaxf(m, 0.2f * m);
          float pm = m * attv[nt];
          if (nt < 2) p0 += pm;
          else if (nt < 4) p1 += pm;
          else if (nt < 6) p2 += pm;
          else p3 += pm;
        }
        uint pa = pk2(p0, p1), pb = pk2(p2, p3);
#pragma unroll
        for (int o = 1; o <= 8; o <<= 1) {
          pa = swz_add(pa, o);
          pb = swz_add(pb, o);
        }
        float2 sA = __half22float2(*(__half2*)&pa);
        float2 sB = __half22float2(*(__half2*)&pb);
        float w0 = exp2f(fminf(sA.x, 115.f));
        float w1 = exp2f(fminf(sA.y, 115.f));
        float w2 = exp2f(fminf(sB.x, 115.f));
        float w3 = exp2f(fminf(sB.y, 115.f));
        if (t0 + 4 * lg + r >= re) { w0 = 0.f; w1 = 0.f; w2 = 0.f; w3 = 0.f; }
        d0 += w0; d1 += w1; d2 += w2; d3 += w3;
#pragma unroll
        for (int nt = 0; nt < 8; ++nt) {
          float wn = (nt < 2) ? w0 : (nt < 4) ? w1 : (nt < 6) ? w2 : w3;
          acc[nt] += wn * xv[nt];
        }
      }
    } else {
#pragma unroll
      for (int rp = 0; rp < 2; ++rp) {
        const int ra = 2 * rp, rbx = 2 * rp + 1;
        float xva[8], xvb[8];
#pragma unroll
        for (int q = 0; q < 4; ++q) {
          float2 fa = __half22float2(*(__half2*)&u[ra][q]);
          float2 fb = __half22float2(*(__half2*)&u[rbx][q]);
          xva[q] = fa.x; xva[q + 4] = fa.y;
          xvb[q] = fb.x; xvb[q + 4] = fb.y;
        }
        float pA = 0.f, pB = 0.f;
#pragma unroll
        for (int nt = 0; nt < 8; ++nt) {
          float ma = D[nt][ra] + xrv[nt] + xva[nt];
          float mb = D[nt][rbx] + xrv[nt] + xvb[nt];
          ma = fmaxf(ma, 0.2f * ma);
          mb = fmaxf(mb, 0.2f * mb);
          pA += ma * attv[nt];
          pB += mb * attv[nt];
        }
        uint pa = pk2(pA, pB);
#pragma unroll
        for (int o = 1; o <= 8; o <<= 1) pa = swz_add(pa, o);
        float2 s = __half22float2(*(__half2*)&pa);
        float w0 = exp2f(fminf(s.x, 115.f));
        float w1 = exp2f(fminf(s.y, 115.f));
        if (t0 + 4 * lg + ra >= re) w0 = 0.f;
        if (t0 + 4 * lg + rbx >= re) w1 = 0.f;
        d0 += w0 + w1;
#pragma unroll
        for (int nt = 0; nt < 8; ++nt) acc[nt] += w0 * xva[nt] + w1 * xvb[nt];
      }
    }
  }

  // cross-group combine (groups processed distinct edge rows)
#pragma unroll
  for (int o = 16; o <= 32; o <<= 1) {
#pragma unroll
    for (int nt = 0; nt < 8; ++nt) acc[nt] += __shfl_xor(acc[nt], o);
    d0 += __shfl_xor(d0, o);
    if (H == 4) {
      d1 += __shfl_xor(d1, o);
      d2 += __shfl_xor(d2, o);
      d3 += __shfl_xor(d3, o);
    }
  }

  const float rd0 = (d0 > 0.f) ? 1.f / d0 : 0.f;
  const float rd1 = (H == 4) ? ((d1 > 0.f) ? 1.f / d1 : 0.f) : rd0;
  const float rd2 = (H == 4) ? ((d2 > 0.f) ? 1.f / d2 : 0.f) : rd0;
  const float rd3 = (H == 4) ? ((d3 > 0.f) ? 1.f / d3 : 0.f) : rd0;

  float y[8];
  float s1 = 0.f, s2 = 0.f;
#pragma unroll
  for (int nt = 0; nt < 8; ++nt) {
    const int c = lr + 16 * nt;
    const float rdn = (H == 1) ? rd0 : ((nt < 2) ? rd0 : (nt < 4) ? rd1 : (nt < 6) ? rd2 : rd3);
    y[nt] = acc[nt] * rdn + bias[c];
    s1 += y[nt];
    s2 += y[nt] * y[nt];
  }
#pragma unroll
  for (int o = 1; o <= 8; o <<= 1) {  // 16-lane group holds all 128 cols
    s1 += __shfl_xor(s1, o);
    s2 += __shfl_xor(s2, o);
  }
  const float mu = s1 * (1.f / 128.f);
  const float var = s2 * (1.f / 128.f) - mu * mu;
  const float rstd = rsqrtf(var + 1e-5f);
  if (lg == 0) {  // groups hold identical data; one stores
#pragma unroll
    for (int nt = 0; nt < 8; ++nt) {
      const int c = lr + 16 * nt;
      const float o0 = fmaxf((y[nt] - mu) * rstd * gam[c] + bet[c], 0.f);
      if (OB)
        outb[(size_t)n * 128 + c] = f2bf(o0);
      else
        out[(size_t)n * 128 + c] = o0;
    }
  }
}

extern "C" void kernel_launch(void* const* d_in, const int* in_sizes, int n_in,
                              void* d_out, int out_size, void* d_ws, size_t ws_size,
                              hipStream_t stream) {
  const float* x = (const float*)d_in[0];
  const float* ea = (const float*)d_in[1];
  const int* src = (const int*)d_in[2];
  const int* dst = (const int*)d_in[3];
  const int N = in_sizes[0] / 128;
  const int E = in_sizes[2];

  char* w = (char*)d_ws;
  auto alloc = [&](size_t bytes) {
    char* p = w;
    w += (bytes + 255) & ~(size_t)255;
    return p;
  };
  ushort* xlh = (ushort*)alloc((size_t)N * 128 * 2);
  float* xr = (float*)alloc((size_t)N * 128 * 4);
  ushort* xb = (ushort*)alloc((size_t)N * 128 * 2);
  ushort* wt1 = (ushort*)alloc(128 * 128 * 2);
  ushort* wt2 = (ushort*)alloc(128 * 128 * 2);
  ushort* weh = (ushort*)alloc(128 * 32 * 2);
  int* eperm = (int*)alloc((size_t)E * 4);
  int* rowptr = (int*)alloc((size_t)(N + 1) * 4);
  int* deg = (int*)alloc((size_t)N * 4);
  int* cnt = (int*)alloc((size_t)N * 4);
  int* nodeorder = (int*)alloc((size_t)N * 4);
  int* dh = (int*)alloc(256 * 4);
  int* dbase = (int*)alloc(256 * 4);
  int* dcnt = (int*)alloc(256 * 4);
  int* bsum = (int*)alloc(1024 * 4);
  ushort* ea16 = (ushort*)alloc((size_t)E * 32 * 2);
  int* src_perm = (int*)alloc((size_t)E * 4);
  size_t used = (size_t)(w - (char*)d_ws);
  const bool SPLIT_OK = (used + (size_t)E * 32 * 2 + 256 <= ws_size);
  ushort* tmp16 = nullptr;
  if (SPLIT_OK) tmp16 = (ushort*)alloc((size_t)E * 32 * 2);

  hipMemsetAsync(deg, 0, (size_t)N * 4, stream);
  hipMemsetAsync(cnt, 0, (size_t)N * 4, stream);
  hipMemsetAsync(dh, 0, 256 * 4, stream);
  hipMemsetAsync(dcnt, 0, 256 * 4, stream);
  hist_kernel<<<(E + 255) / 256, 256, 0, stream>>>(dst, deg, E);
  int nb = (N + 1023) / 1024;
  scan_blocks<<<nb, 1024, 0, stream>>>(deg, rowptr, bsum, N);
  scan_carry<<<1, 64, 0, stream>>>(bsum, nb);
  scan_apply<<<nb, 1024, 0, stream>>>(rowptr, bsum, N);
  scatter_kernel<<<(E + 255) / 256, 256, 0, stream>>>(dst, rowptr, cnt, eperm, E);
  deg_hist<<<(N + 255) / 256, 256, 0, stream>>>(rowptr, dh, N);
  deg_scan<<<1, 256, 0, stream>>>(dh, dbase);
  deg_scatter<<<(N + 255) / 256, 256, 0, stream>>>(rowptr, dbase, dcnt, nodeorder, N);

  if (SPLIT_OK) {
    convert_ea<<<(E * 4 + 255) / 256, 256, 0, stream>>>(ea, tmp16, E * 4);
    permute_ea<<<((size_t)E * 4 + 255) / 256, 256, 0, stream>>>(tmp16, eperm, src,
                                                                ea16, src_perm, E);
  } else {
    prep_edges_h<<<((size_t)E * 8 + 255) / 256, 256, 0, stream>>>(ea, eperm, src,
                                                                  ea16, src_perm, E);
  }

  int n8 = N * 128 / 8;
  convert_x<<<(n8 + 255) / 256, 256, 0, stream>>>(x, xb, n8);

  for (int l = 0; l < 3; ++l) {
    int bi = 4 + 9 * l;
    const float* Wl = (const float*)d_in[bi + 0];
    const float* bl = (const float*)d_in[bi + 1];
    const float* Wr = (const float*)d_in[bi + 2];
    const float* br = (const float*)d_in[bi + 3];
    const float* We = (const float*)d_in[bi + 4];
    const float* att = (const float*)d_in[bi + 5];
    const float* bo = (const float*)d_in[bi + 6];
    const float* gg = (const float*)d_in[bi + 7];
    const float* be = (const float*)d_in[bi + 8];

    prep_w<<<128, 256, 0, stream>>>(Wl, Wr, wt1, wt2);
    prep_we<<<16, 256, 0, stream>>>(We, weh);
    gemm_mfma_dual<<<(N + 127) / 128, 512, 0, stream>>>(xb, wt1, wt2, bl, br, xlh, xr, N);
    if (l < 2) {
      fused_gat<4, true><<<N, 64, 0, stream>>>(xlh, xr, ea16, weh, att, rowptr,
                                               src_perm, nodeorder, bo, gg, be,
                                               nullptr, xb, N);
    } else {
      fused_gat<1, false><<<N, 64, 0, stream>>>(xlh, xr, ea16, weh, att, rowptr,
                                                src_perm, nodeorder, bo, gg, be,
                                                (float*)d_out, nullptr, N);
    }
  }
}